// Round 1
// 939.293 us; speedup vs baseline: 1.0445x; 1.0445x over previous
//
#include <hip/hip_runtime.h>

#define Bq 8
#define Tq 2048
#define Cq 1024
#define Hq 16
#define Nq 64
#define FFNq 3584
#define EPSq 1e-5f

typedef __bf16 bf8v __attribute__((ext_vector_type(8)));
typedef float f32x4 __attribute__((ext_vector_type(4)));

typedef __attribute__((address_space(1))) const unsigned int GU;
typedef __attribute__((address_space(3))) unsigned int LU;

__device__ __forceinline__ void gload16(const unsigned short* g, unsigned short* l) {
    __builtin_amdgcn_global_load_lds((GU*)g, (LU*)l, 16, 0, 0);
}

__device__ __forceinline__ unsigned short f2bf(float f) {
    unsigned u = __float_as_uint(f);
    u += 0x7fffu + ((u >> 16) & 1u);   // round-to-nearest-even
    return (unsigned short)(u >> 16);
}
__device__ __forceinline__ float bf2f(unsigned short h) {
    return __uint_as_float(((unsigned)h) << 16);
}

// ---------------- diagnostic fill (ws too small) ----------------
__global__ __launch_bounds__(256)
void diag_kernel(float* __restrict__ out, float val) {
    int i = (blockIdx.x * 256 + threadIdx.x) * 4;
    float4 v = make_float4(val, val, val, val);
    *(float4*)(out + i) = v;
}

// ---------------- fp32 -> bf16 conversion, all 8 weights in one launch -------
__global__ __launch_bounds__(256)
void f2bf_all_kernel(const float* __restrict__ s0, const float* __restrict__ s1,
                     const float* __restrict__ s2, const float* __restrict__ s3,
                     const float* __restrict__ s4, const float* __restrict__ s5,
                     const float* __restrict__ s6, const float* __restrict__ s7,
                     unsigned short* __restrict__ d0, unsigned short* __restrict__ d1,
                     unsigned short* __restrict__ d2, unsigned short* __restrict__ d3,
                     unsigned short* __restrict__ d4, unsigned short* __restrict__ d5,
                     unsigned short* __restrict__ d6, unsigned short* __restrict__ d7) {
    int b = blockIdx.x;
    const float* src; unsigned short* dst;
    if      (b < 1024)  { src = s0; dst = d0; }
    else if (b < 2048)  { src = s1; dst = d1; b -= 1024; }
    else if (b < 3072)  { src = s2; dst = d2; b -= 2048; }
    else if (b < 4096)  { src = s3; dst = d3; b -= 3072; }
    else if (b < 5120)  { src = s4; dst = d4; b -= 4096; }
    else if (b < 8704)  { src = s5; dst = d5; b -= 5120; }
    else if (b < 9728)  { src = s6; dst = d6; b -= 8704; }
    else                { src = s7; dst = d7; b -= 9728; }
    int i = (b * 256 + threadIdx.x) * 4;
    float4 v = *(const float4*)(src + i);
    ushort4 o;
    o.x = f2bf(v.x); o.y = f2bf(v.y); o.z = f2bf(v.z); o.w = f2bf(v.w);
    *(ushort4*)(dst + i) = o;
}

// ---------------- block reduction helper (256 threads) ----------------
__device__ __forceinline__ void blockred2(float& a, float& b, float* sm) {
#pragma unroll
    for (int m = 1; m < 64; m <<= 1) { a += __shfl_xor(a, m); b += __shfl_xor(b, m); }
    const int w = threadIdx.x >> 6;
    __syncthreads();
    if ((threadIdx.x & 63) == 0) { sm[w] = a; sm[4 + w] = b; }
    __syncthreads();
    a = sm[0] + sm[1] + sm[2] + sm[3];
    b = sm[4] + sm[5] + sm[6] + sm[7];
}

// ---------------- ln0 + ln1 fused: x -> x0 (fp32), xn (bf16) ----------------
__global__ __launch_bounds__(256)
void ln01_kernel(const float* __restrict__ x,
                 const float* __restrict__ w0, const float* __restrict__ b0,
                 const float* __restrict__ w1, const float* __restrict__ b1,
                 float* __restrict__ x0, unsigned short* __restrict__ xn) {
    __shared__ float sm[8];
    const int tok = blockIdx.x, tid = threadIdx.x, c = tid * 4;
    const size_t base = (size_t)tok * Cq + c;
    float4 v = *(const float4*)(x + base);
    float s = v.x + v.y + v.z + v.w;
    float ss = v.x * v.x + v.y * v.y + v.z * v.z + v.w * v.w;
    blockred2(s, ss, sm);
    float mu = s * (1.f / Cq);
    float rstd = rsqrtf(ss * (1.f / Cq) - mu * mu + EPSq);
    float4 wv = *(const float4*)(w0 + c), bv = *(const float4*)(b0 + c);
    float4 e;
    e.x = (v.x - mu) * rstd * wv.x + bv.x;
    e.y = (v.y - mu) * rstd * wv.y + bv.y;
    e.z = (v.z - mu) * rstd * wv.z + bv.z;
    e.w = (v.w - mu) * rstd * wv.w + bv.w;
    *(float4*)(x0 + base) = e;
    s = e.x + e.y + e.z + e.w;
    ss = e.x * e.x + e.y * e.y + e.z * e.z + e.w * e.w;
    blockred2(s, ss, sm);
    mu = s * (1.f / Cq);
    rstd = rsqrtf(ss * (1.f / Cq) - mu * mu + EPSq);
    wv = *(const float4*)(w1 + c); bv = *(const float4*)(b1 + c);
    ushort4 o;
    o.x = f2bf((e.x - mu) * rstd * wv.x + bv.x);
    o.y = f2bf((e.y - mu) * rstd * wv.y + bv.y);
    o.z = f2bf((e.z - mu) * rstd * wv.z + bv.z);
    o.w = f2bf((e.w - mu) * rstd * wv.w + bv.w);
    *(ushort4*)(xn + base) = o;
}

// ---------------- single layernorm (ln2): fp32 in -> bf16 out ----------------
__global__ __launch_bounds__(256)
void ln_kernel(const float* __restrict__ x, const float* __restrict__ w,
               const float* __restrict__ b, unsigned short* __restrict__ out) {
    __shared__ float sm[8];
    const int tok = blockIdx.x, tid = threadIdx.x, c = tid * 4;
    const size_t base = (size_t)tok * Cq + c;
    float4 v = *(const float4*)(x + base);
    float s = v.x + v.y + v.z + v.w;
    float ss = v.x * v.x + v.y * v.y + v.z * v.z + v.w * v.w;
    blockred2(s, ss, sm);
    float mu = s * (1.f / Cq);
    float rstd = rsqrtf(ss * (1.f / Cq) - mu * mu + EPSq);
    float4 wv = *(const float4*)(w + c), bv = *(const float4*)(b + c);
    ushort4 o;
    o.x = f2bf((v.x - mu) * rstd * wv.x + bv.x);
    o.y = f2bf((v.y - mu) * rstd * wv.y + bv.y);
    o.z = f2bf((v.z - mu) * rstd * wv.z + bv.z);
    o.w = f2bf((v.w - mu) * rstd * wv.w + bv.w);
    *(ushort4*)(out + base) = o;
}

// ---------------- token-shift: 4 mixes in one pass (time-mix) ----------------
__device__ __forceinline__ ushort4 mixpack(float ax, float ay, float az, float aw,
                                           float px, float py, float pz, float pw,
                                           const float4& m) {
    ushort4 o;
    o.x = f2bf(px + m.x * (ax - px));
    o.y = f2bf(py + m.y * (ay - py));
    o.z = f2bf(pz + m.z * (az - pz));
    o.w = f2bf(pw + m.w * (aw - pw));
    return o;
}

__global__ __launch_bounds__(256)
void mix4_kernel(const unsigned short* __restrict__ xn,
                 const float* __restrict__ tmr, const float* __restrict__ tmk,
                 const float* __restrict__ tmv, const float* __restrict__ tmg,
                 ushort4* __restrict__ outR, ushort4* __restrict__ outK,
                 ushort4* __restrict__ outV, ushort4* __restrict__ outG) {
    const int tok = blockIdx.x, tid = threadIdx.x, c = tid * 4;
    const int t = tok & (Tq - 1);
    const size_t base = (size_t)tok * Cq + c;
    ushort4 a = *(const ushort4*)(xn + base);
    ushort4 p = make_ushort4(0, 0, 0, 0);
    if (t) p = *(const ushort4*)(xn + base - Cq);
    float ax = bf2f(a.x), ay = bf2f(a.y), az = bf2f(a.z), aw = bf2f(a.w);
    float px = bf2f(p.x), py = bf2f(p.y), pz = bf2f(p.z), pw = bf2f(p.w);
    const size_t b4 = (size_t)tok * 256 + tid;
    outR[b4] = mixpack(ax, ay, az, aw, px, py, pz, pw, *(const float4*)(tmr + c));
    outK[b4] = mixpack(ax, ay, az, aw, px, py, pz, pw, *(const float4*)(tmk + c));
    outV[b4] = mixpack(ax, ay, az, aw, px, py, pz, pw, *(const float4*)(tmv + c));
    outG[b4] = mixpack(ax, ay, az, aw, px, py, pz, pw, *(const float4*)(tmg + c));
}

// ---------------- token-shift: 2 mixes in one pass (channel-mix) -------------
__global__ __launch_bounds__(256)
void mix2_kernel(const unsigned short* __restrict__ xn,
                 const float* __restrict__ tmk, const float* __restrict__ tmr,
                 ushort4* __restrict__ outK, ushort4* __restrict__ outR) {
    const int tok = blockIdx.x, tid = threadIdx.x, c = tid * 4;
    const int t = tok & (Tq - 1);
    const size_t base = (size_t)tok * Cq + c;
    ushort4 a = *(const ushort4*)(xn + base);
    ushort4 p = make_ushort4(0, 0, 0, 0);
    if (t) p = *(const ushort4*)(xn + base - Cq);
    float ax = bf2f(a.x), ay = bf2f(a.y), az = bf2f(a.z), aw = bf2f(a.w);
    float px = bf2f(p.x), py = bf2f(p.y), pz = bf2f(p.z), pw = bf2f(p.w);
    const size_t b4 = (size_t)tok * 256 + tid;
    outK[b4] = mixpack(ax, ay, az, aw, px, py, pz, pw, *(const float4*)(tmk + c));
    outR[b4] = mixpack(ax, ay, az, aw, px, py, pz, pw, *(const float4*)(tmr + c));
}

// ---------------- 256x256 phase-pipelined bf16 MFMA GEMM ---------------------
// out[m,n] = sum_k A[m,k]*W[n,k].  8 waves (2Mx4N), per-wave 128x64 output.
// BK=32; LDS = 4-slot ring x {A,B} x 16KB = 128 KiB (1 block/CU, 2 waves/SIMD).
// Pipeline: stage K-tile t+3 while computing t; raw s_barrier (no vmcnt drain);
// counted s_waitcnt vmcnt(8) once per tile (2 tiles stay in flight across
// barriers); tail drains 8->4->0.  LDS XOR-swizzle byte^=((row&3)<<4) applied
// to BOTH the pre-swizzled global staging source and the ds_read_b128 frag
// reads (8-way -> 4-way quarter-wave conflicts; linear gload_lds dest kept).
// MODE: 1 silu->bf16; 2 res+acc->fp32; 3 relu^2->bf16; 4 sigmoid->bf16;
//       5 res+bf2f(sg)*acc->fp32; 6 plain->bf16.  Requires K%32==0, K>=128,
//       M%256==0, N%256==0, grid%8==0 (all call sites satisfy).
template<int MODE>
__global__ __launch_bounds__(512, 2)
void gemm256(const unsigned short* __restrict__ A, const unsigned short* __restrict__ W,
             int K, int N, float* __restrict__ outF, unsigned short* __restrict__ outB,
             const float* __restrict__ res, const unsigned short* __restrict__ sg) {
    __shared__ unsigned short lds[4][2][8192];   // [slot][A=0/B=1][256*32 elems]
    const int tid = threadIdx.x;
    const int wid = tid >> 6, lane = tid & 63;
    const int wr = wid >> 2, wc = wid & 3;       // wave grid 2 (M) x 4 (N)
    const int l15 = lane & 15, q = lane >> 4;

    // T1: bijective XCD swizzle (grid % 8 == 0), then m-major over nn n-blocks
    const int nn = N >> 8;
    const int q8 = gridDim.x >> 3;
    const int bid = blockIdx.x;
    const int swz = (bid & 7) * q8 + (bid >> 3);
    const int m0 = (swz / nn) * 256;
    const int n0 = (swz % nn) * 256;

    // staging: thread's linear LDS dest d -> pre-swizzled global source
    const int d0 = tid * 16, d1 = 8192 + tid * 16;           // bytes in 16KB region
    const int p0 = d0 ^ (((d0 >> 6) & 3) << 4);
    const int p1 = d1 ^ (((d1 >> 6) & 3) << 4);
    const int r0 = p0 >> 6, c0 = (p0 >> 1) & 31;             // rows 0..127
    const int r1 = p1 >> 6, c1 = (p1 >> 1) & 31;             // rows 128..255
    const unsigned short* a0 = A + (size_t)(m0 + r0) * K + c0;
    const unsigned short* a1 = A + (size_t)(m0 + r1) * K + c1;
    const unsigned short* w0 = W + (size_t)(n0 + r0) * K + c0;
    const unsigned short* w1 = W + (size_t)(n0 + r1) * K + c1;

    // fragment read offsets (elems), swizzled k-chunk: (q ^ (row&3))
    const int cOff = (q ^ (l15 & 3)) * 8;
    const int aBase = (wr * 128 + l15) * 32 + cOff;
    const int bBase = (wc * 64 + l15) * 32 + cOff;

    f32x4 acc[8][4];
#pragma unroll
    for (int mi = 0; mi < 8; ++mi)
#pragma unroll
        for (int ni = 0; ni < 4; ++ni)
            acc[mi][ni] = {0.f, 0.f, 0.f, 0.f};

    const int NT = K >> 5;

    // prologue: stage tiles 0,1,2 (12 loads) -> wait 4 oldest (tile 0) landed
#pragma unroll
    for (int t = 0; t < 3; ++t) {
        unsigned short* La = (unsigned short*)&lds[t][0][wid * 512];
        unsigned short* Lb = (unsigned short*)&lds[t][1][wid * 512];
        gload16(a0, La); gload16(a1, La + 4096);
        gload16(w0, Lb); gload16(w1, Lb + 4096);
        a0 += 32; a1 += 32; w0 += 32; w1 += 32;
    }
    asm volatile("s_waitcnt vmcnt(8)" ::: "memory");
    __builtin_amdgcn_s_barrier();

    for (int t = 0; t < NT; ++t) {
        const int slot = t & 3;
        const bool st = (t + 3) < NT;
        const int ps = (t + 3) & 3;
        bf8v af[4], bb[4];

        // ---- phase 1: read af[0:4] + b[0:4] (8 ds_read), stage A(t+3),
        //      16 MFMA (mi 0..3 x ni 0..3) ----
#pragma unroll
        for (int mi = 0; mi < 4; ++mi)
            af[mi] = *(const bf8v*)&lds[slot][0][aBase + mi * 512];
#pragma unroll
        for (int ni = 0; ni < 4; ++ni)
            bb[ni] = *(const bf8v*)&lds[slot][1][bBase + ni * 512];
        if (st) {
            unsigned short* La = (unsigned short*)&lds[ps][0][wid * 512];
            gload16(a0, La); gload16(a1, La + 4096);
            a0 += 32; a1 += 32;
        }
        __builtin_amdgcn_s_barrier();
        __builtin_amdgcn_s_setprio(1);
#pragma unroll
        for (int mi = 0; mi < 4; ++mi)
#pragma unroll
            for (int ni = 0; ni < 4; ++ni)
                acc[mi][ni] = __builtin_amdgcn_mfma_f32_16x16x32_bf16(af[mi], bb[ni], acc[mi][ni], 0, 0, 0);
        __builtin_amdgcn_s_setprio(0);
        __builtin_amdgcn_s_barrier();

        // ---- phase 2: read af[4:8] (4 ds_read), stage B(t+3),
        //      16 MFMA (mi 4..7 x ni 0..3) ----
#pragma unroll
        for (int mi = 0; mi < 4; ++mi)
            af[mi] = *(const bf8v*)&lds[slot][0][aBase + (4 + mi) * 512];
        if (st) {
            unsigned short* Lb = (unsigned short*)&lds[ps][1][wid * 512];
            gload16(w0, Lb); gload16(w1, Lb + 4096);
            w0 += 32; w1 += 32;
        }
        __builtin_amdgcn_s_barrier();
        __builtin_amdgcn_s_setprio(1);
#pragma unroll
        for (int mi = 0; mi < 4; ++mi)
#pragma unroll
            for (int ni = 0; ni < 4; ++ni)
                acc[4 + mi][ni] = __builtin_amdgcn_mfma_f32_16x16x32_bf16(af[mi], bb[ni], acc[4 + mi][ni], 0, 0, 0);
        __builtin_amdgcn_s_setprio(0);
        // counted wait BEFORE the tile-end barrier: after the barrier every
        // wave's loads for tile t+1 have landed.  never 0 in steady state.
        if (t < NT - 3)       { asm volatile("s_waitcnt vmcnt(8)" ::: "memory"); }
        else if (t == NT - 3) { asm volatile("s_waitcnt vmcnt(4)" ::: "memory"); }
        else if (t == NT - 2) { asm volatile("s_waitcnt vmcnt(0)" ::: "memory"); }
        __builtin_amdgcn_s_barrier();
    }

    // ---- epilogue ----
#pragma unroll
    for (int mi = 0; mi < 8; ++mi)
#pragma unroll
        for (int ni = 0; ni < 4; ++ni)
#pragma unroll
            for (int j = 0; j < 4; ++j) {
                const int row = m0 + wr * 128 + mi * 16 + q * 4 + j;
                const int col = n0 + wc * 64 + ni * 16 + l15;
                const size_t idx = (size_t)row * N + col;
                const float a = acc[mi][ni][j];
                if (MODE == 1) {
                    outB[idx] = f2bf(a / (1.f + __expf(-a)));
                } else if (MODE == 2) {
                    outF[idx] = res[idx] + a;
                } else if (MODE == 3) {
                    float tt = fmaxf(a, 0.f);
                    outB[idx] = f2bf(tt * tt);
                } else if (MODE == 4) {
                    outB[idx] = f2bf(1.f / (1.f + __expf(-a)));
                } else if (MODE == 5) {
                    outF[idx] = res[idx] + bf2f(sg[idx]) * a;
                } else {
                    outB[idx] = f2bf(a);
                }
            }
}

// ---------------- WKV5: chunked linear attention + fused GroupNorm*gate ------
__global__ __launch_bounds__(256)
void wkv_kernel(const unsigned short* __restrict__ r, const unsigned short* __restrict__ k,
                const unsigned short* __restrict__ v, const unsigned short* __restrict__ g,
                const float* __restrict__ decay, const float* __restrict__ faaaa,
                const float* __restrict__ lnxw, const float* __restrict__ lnxb,
                unsigned short* __restrict__ ao) {
    __shared__ unsigned short rp[64 * 72], km[64 * 72], kdT[64 * 72];
    __shared__ unsigned short VT[64 * 72], Abf[64 * 72], ScT[64 * 72], Gsh[64 * 72];
    __shared__ float Dt[64];
    const int tid = threadIdx.x;
    const int bh = blockIdx.x, b = bh >> 4, h = bh & 15;
    const int tr = tid >> 2, g4 = tid & 3, i0 = g4 * 16;
    const int wv = tid >> 6, lane = tid & 63, l15 = lane & 15, q = lane >> 4;
    const float LOG2E = 1.44269504088896340736f;

    float l2w[16], uu[16];
#pragma unroll
    for (int ii = 0; ii < 16; ++ii) {
        l2w[ii] = -__expf(decay[h * Nq + i0 + ii]) * LOG2E;
        uu[ii] = faaaa[h * Nq + i0 + ii];
    }
    float ewL[4];
#pragma unroll
    for (int jr = 0; jr < 4; ++jr) {
        float lw = -__expf(decay[h * Nq + 16 * wv + q * 4 + jr]) * LOG2E;
        ewL[jr] = exp2f(64.f * lw);
    }
    const int colbase = h * Nq;
    float lwj[4], lbj[4];
#pragma unroll
    for (int nt = 0; nt < 4; ++nt) {
        lwj[nt] = lnxw[colbase + 16 * nt + l15];
        lbj[nt] = lnxb[colbase + 16 * nt + l15];
    }
    f32x4 S[4];
#pragma unroll
    for (int nt = 0; nt < 4; ++nt) S[nt] = {0.f, 0.f, 0.f, 0.f};
    for (int idx = tid; idx < 64 * 72; idx += 256) ScT[idx] = 0;
    __syncthreads();

    const size_t rowbase = (size_t)b * Tq;

    for (int c = 0; c < 32; ++c) {
        const size_t grow = (rowbase + c * 64 + tr) * Cq + colbase + i0;
        unsigned short rs_[16], ks_[16], vs_[16];
        *(uint4*)&rs_[0] = *(const uint4*)(r + grow);
        *(uint4*)&rs_[8] = *(const uint4*)(r + grow + 8);
        *(uint4*)&ks_[0] = *(const uint4*)(k + grow);
        *(uint4*)&ks_[8] = *(const uint4*)(k + grow + 8);
        *(uint4*)&vs_[0] = *(const uint4*)(v + grow);
        *(uint4*)&vs_[8] = *(const uint4*)(v + grow + 8);
        *(uint4*)&Gsh[tr * 72 + i0] = *(const uint4*)(g + grow);
        *(uint4*)&Gsh[tr * 72 + i0 + 8] = *(const uint4*)(g + grow + 8);
        float pd = 0.f;
        const float ftr = (float)tr;
#pragma unroll
        for (int ii = 0; ii < 16; ++ii) {
            float rf = bf2f(rs_[ii]), kf = bf2f(ks_[ii]);
            rp[tr * 72 + i0 + ii] = f2bf(rf * exp2f(ftr * l2w[ii]));
            km[tr * 72 + i0 + ii] = f2bf(kf * exp2f(-(ftr + 1.f) * l2w[ii]));
            kdT[(i0 + ii) * 72 + tr] = f2bf(kf * exp2f((63.f - ftr) * l2w[ii]));
            VT[(i0 + ii) * 72 + tr] = vs_[ii];
            pd += rf * uu[ii] * kf;
        }
        pd += __shfl_xor(pd, 1);
        pd += __shfl_xor(pd, 2);
        if (g4 == 0) Dt[tr] = pd;
        __syncthreads();

        f32x4 accA[4];
#pragma unroll
        for (int nt = 0; nt < 4; ++nt) accA[nt] = {0.f, 0.f, 0.f, 0.f};
#pragma unroll
        for (int ks = 0; ks < 2; ++ks) {
            bf8v a = *(const bf8v*)&rp[(16 * wv + l15) * 72 + ks * 32 + q * 8];
#pragma unroll
            for (int nt = 0; nt < 4; ++nt) {
                bf8v bbv = *(const bf8v*)&km[(16 * nt + l15) * 72 + ks * 32 + q * 8];
                accA[nt] = __builtin_amdgcn_mfma_f32_16x16x32_bf16(a, bbv, accA[nt], 0, 0, 0);
            }
        }
#pragma unroll
        for (int nt = 0; nt < 4; ++nt)
#pragma unroll
            for (int jr = 0; jr < 4; ++jr) {
                const int t = 16 * wv + q * 4 + jr, s = 16 * nt + l15;
                const float a = accA[nt][jr];
                const float val = (s < t) ? a : ((s == t) ? Dt[t] : 0.f);
                Abf[t * 72 + s] = f2bf(val);
            }

        f32x4 accY[4];
#pragma unroll
        for (int nt = 0; nt < 4; ++nt) accY[nt] = {0.f, 0.f, 0.f, 0.f};
#pragma unroll
        for (int ks = 0; ks < 2; ++ks) {
            bf8v a = *(const bf8v*)&Abf[(16 * wv + l15) * 72 + ks * 32 + q * 8];
#pragma unroll
            for (int nt = 0; nt < 4; ++nt) {
                bf8v bbv = *(const bf8v*)&VT[(16 * nt + l15) * 72 + ks * 32 + q * 8];
                accY[nt] = __builtin_amdgcn_mfma_f32_16x16x32_bf16(a, bbv, accY[nt], 0, 0, 0);
            }
        }
#pragma unroll
        for (int ks = 0; ks < 2; ++ks) {
            bf8v a = *(const bf8v*)&rp[(16 * wv + l15) * 72 + ks * 32 + q * 8];
#pragma unroll
            for (int nt = 0; nt < 4; ++nt) {
                bf8v bbv = *(const bf8v*)&ScT[(16 * nt + l15) * 72 + ks * 32 + q * 8];
                accY[nt] = __builtin_amdgcn_mfma_f32_16x16x32_bf16(a, bbv, accY[nt], 0, 0, 0);
            }
        }

        float sum_[4] = {0.f, 0.f, 0.f, 0.f}, sq_[4] = {0.f, 0.f, 0.f, 0.f};
#pragma unroll
        for (int nt = 0; nt < 4; ++nt)
#pragma unroll
            for (int jr = 0; jr < 4; ++jr) {
                float yv = accY[nt][jr] * 0.125f;
                accY[nt][jr] = yv;
                sum_[jr] += yv;
                sq_[jr] += yv * yv;
            }
#pragma unroll
        for (int m = 1; m < 16; m <<= 1)
#pragma unroll
            for (int jr = 0; jr < 4; ++jr) {
                sum_[jr] += __shfl_xor(sum_[jr], m);
                sq_[jr] += __shfl_xor(sq_[jr], m);
            }
        float mu_[4], rstd_[4];
#pragma unroll
        for (int jr = 0; jr < 4; ++jr) {
            mu_[jr] = sum_[jr] * (1.f / Nq);
            rstd_[jr] = rsqrtf(sq_[jr] * (1.f / Nq) - mu_[jr] * mu_[jr] + EPSq);
        }
#pragma unroll
        for (int nt = 0; nt < 4; ++nt)
#pragma unroll
            for (int jr = 0; jr < 4; ++jr) {
                const int t = 16 * wv + q * 4 + jr;
                const float gate = bf2f(Gsh[t * 72 + 16 * nt + l15]);
                const float val = (accY[nt][jr] - mu_[jr]) * rstd_[jr] * lwj[nt] + lbj[nt];
                ao[(rowbase + c * 64 + t) * Cq + colbase + 16 * nt + l15] = f2bf(val * gate);
            }

        f32x4 accU[4];
#pragma unroll
        for (int nt = 0; nt < 4; ++nt) accU[nt] = {0.f, 0.f, 0.f, 0.f};
#pragma unroll
        for (int ks = 0; ks < 2; ++ks) {
            bf8v a = *(const bf8v*)&kdT[(16 * wv + l15) * 72 + ks * 32 + q * 8];
#pragma unroll
            for (int nt = 0; nt < 4; ++nt) {
                bf8v bbv = *(const bf8v*)&VT[(16 * nt + l15) * 72 + ks * 32 + q * 8];
                accU[nt] = __builtin_amdgcn_mfma_f32_16x16x32_bf16(a, bbv, accU[nt], 0, 0, 0);
            }
        }
        __syncthreads();
#pragma unroll
        for (int nt = 0; nt < 4; ++nt) {
#pragma unroll
            for (int jr = 0; jr < 4; ++jr)
                S[nt][jr] = ewL[jr] * S[nt][jr] + accU[nt][jr];
            ushort4 sc;
            sc.x = f2bf(S[nt][0]); sc.y = f2bf(S[nt][1]);
            sc.z = f2bf(S[nt][2]); sc.w = f2bf(S[nt][3]);
            *(ushort4*)&ScT[(16 * nt + l15) * 72 + 16 * wv + q * 4] = sc;
        }
        __syncthreads();
    }
}

// ---------------- launcher ----------------
extern "C" void kernel_launch(void* const* d_in, const int* in_sizes, int n_in,
                              void* d_out, int out_size, void* d_ws, size_t ws_size,
                              hipStream_t stream) {
    const float* x     = (const float*)d_in[0];
    const float* ln0w  = (const float*)d_in[1];
    const float* ln0b  = (const float*)d_in[2];
    const float* ln1w  = (const float*)d_in[3];
    const float* ln1b  = (const float*)d_in[4];
    const float* ln2w  = (const float*)d_in[5];
    const float* ln2b  = (const float*)d_in[6];
    const float* atmk  = (const float*)d_in[7];
    const float* atmv  = (const float*)d_in[8];
    const float* atmr  = (const float*)d_in[9];
    const float* atmg  = (const float*)d_in[10];
    const float* decay = (const float*)d_in[11];
    const float* faaaa = (const float*)d_in[12];
    const float* aWr   = (const float*)d_in[13];
    const float* aWk   = (const float*)d_in[14];
    const float* aWv   = (const float*)d_in[15];
    const float* aWg   = (const float*)d_in[16];
    const float* aWo   = (const float*)d_in[17];
    const float* lnxw  = (const float*)d_in[18];
    const float* lnxb  = (const float*)d_in[19];
    const float* ftmk  = (const float*)d_in[20];
    const float* ftmr  = (const float*)d_in[21];
    const float* fWk   = (const float*)d_in[22];
    const float* fWr   = (const float*)d_in[23];
    const float* fWv   = (const float*)d_in[24];

    const size_t MB = 1024ull * 1024ull;
    const size_t WS_NEEDED = 250 * MB;
    dim3 blk(256);

    if (ws_size < WS_NEEDED) {
        diag_kernel<<<out_size / 1024, blk, 0, stream>>>((float*)d_out,
            1000.f + (float)((double)ws_size / (double)MB));
        return;
    }

    char* ws = (char*)d_ws;
    unsigned short* WR  = (unsigned short*)(ws + 0 * MB);
    unsigned short* WK  = (unsigned short*)(ws + 2 * MB);
    unsigned short* WV  = (unsigned short*)(ws + 4 * MB);
    unsigned short* WG  = (unsigned short*)(ws + 6 * MB);
    unsigned short* WO  = (unsigned short*)(ws + 8 * MB);
    unsigned short* FWK = (unsigned short*)(ws + 10 * MB);
    unsigned short* FWR = (unsigned short*)(ws + 17 * MB);
    unsigned short* FWV = (unsigned short*)(ws + 19 * MB);
    unsigned short* XN  = (unsigned short*)(ws + 26 * MB);
    unsigned short* MXR = (unsigned short*)(ws + 58 * MB);
    unsigned short* MXK = (unsigned short*)(ws + 90 * MB);
    unsigned short* MXV = (unsigned short*)(ws + 122 * MB);
    unsigned short* MXG = (unsigned short*)(ws + 154 * MB);
    unsigned short* Rb  = (unsigned short*)(ws + 186 * MB);
    unsigned short* Kb  = (unsigned short*)(ws + 58 * MB);
    unsigned short* Vb  = (unsigned short*)(ws + 90 * MB);
    unsigned short* Gb  = (unsigned short*)(ws + 122 * MB);
    unsigned short* AO  = (unsigned short*)(ws + 154 * MB);
    unsigned short* XK2 = (unsigned short*)(ws + 58 * MB);
    unsigned short* XR2 = (unsigned short*)(ws + 90 * MB);
    unsigned short* KF  = (unsigned short*)(ws + 122 * MB);
    unsigned short* SRb = (unsigned short*)(ws + 26 * MB);
    float*          X0  = (float*)d_out;

    const int NTOK = Bq * Tq;  // 16384
    dim3 blk512(512);
    const int gsq = (NTOK / 256) * (Cq / 256);    // 64*4  = 256 blocks
    const int gup = (NTOK / 256) * (FFNq / 256);  // 64*14 = 896 blocks

    f2bf_all_kernel<<<13312, blk, 0, stream>>>(aWr, aWk, aWv, aWg, aWo, fWk, fWr, fWv,
                                               WR, WK, WV, WG, WO, FWK, FWR, FWV);

    ln01_kernel<<<NTOK, blk, 0, stream>>>(x, ln0w, ln0b, ln1w, ln1b, X0, XN);

    mix4_kernel<<<NTOK, blk, 0, stream>>>(XN, atmr, atmk, atmv, atmg,
                                          (ushort4*)MXR, (ushort4*)MXK,
                                          (ushort4*)MXV, (ushort4*)MXG);

    gemm256<6><<<gsq, blk512, 0, stream>>>(MXR, WR, Cq, Cq, nullptr, Rb, nullptr, nullptr);
    gemm256<6><<<gsq, blk512, 0, stream>>>(MXK, WK, Cq, Cq, nullptr, Kb, nullptr, nullptr);
    gemm256<6><<<gsq, blk512, 0, stream>>>(MXV, WV, Cq, Cq, nullptr, Vb, nullptr, nullptr);
    gemm256<1><<<gsq, blk512, 0, stream>>>(MXG, WG, Cq, Cq, nullptr, Gb, nullptr, nullptr);

    wkv_kernel<<<Bq * Hq, blk, 0, stream>>>(Rb, Kb, Vb, Gb, decay, faaaa, lnxw, lnxb, AO);
    gemm256<2><<<gsq, blk512, 0, stream>>>(AO, WO, Cq, Cq, X0, nullptr, X0, nullptr);

    ln_kernel<<<NTOK, blk, 0, stream>>>(X0, ln2w, ln2b, XN);
    mix2_kernel<<<NTOK, blk, 0, stream>>>(XN, ftmk, ftmr, (ushort4*)XK2, (ushort4*)XR2);
    gemm256<3><<<gup, blk512, 0, stream>>>(XK2, FWK, Cq, FFNq, nullptr, KF, nullptr, nullptr);
    gemm256<4><<<gsq, blk512, 0, stream>>>(XR2, FWR, Cq, Cq, nullptr, SRb, nullptr, nullptr);
    gemm256<5><<<gsq, blk512, 0, stream>>>(KF, FWV, FFNq, Cq, X0, nullptr, X0, SRb);
}

// Round 2
// 937.834 us; speedup vs baseline: 1.0461x; 1.0016x over previous
//
#include <hip/hip_runtime.h>

#define Bq 8
#define Tq 2048
#define Cq 1024
#define Hq 16
#define Nq 64
#define FFNq 3584
#define EPSq 1e-5f

typedef __bf16 bf8v __attribute__((ext_vector_type(8)));
typedef float f32x4 __attribute__((ext_vector_type(4)));

typedef __attribute__((address_space(1))) const unsigned int GU;
typedef __attribute__((address_space(3))) unsigned int LU;

__device__ __forceinline__ void gload16(const unsigned short* g, unsigned short* l) {
    __builtin_amdgcn_global_load_lds((GU*)g, (LU*)l, 16, 0, 0);
}

__device__ __forceinline__ unsigned short f2bf(float f) {
    unsigned u = __float_as_uint(f);
    u += 0x7fffu + ((u >> 16) & 1u);   // round-to-nearest-even
    return (unsigned short)(u >> 16);
}
__device__ __forceinline__ float bf2f(unsigned short h) {
    return __uint_as_float(((unsigned)h) << 16);
}

// ---------------- diagnostic fill (ws too small) ----------------
__global__ __launch_bounds__(256)
void diag_kernel(float* __restrict__ out, float val) {
    int i = (blockIdx.x * 256 + threadIdx.x) * 4;
    float4 v = make_float4(val, val, val, val);
    *(float4*)(out + i) = v;
}

// ---------------- fp32 -> bf16 conversion, all 8 weights in one launch -------
__global__ __launch_bounds__(256)
void f2bf_all_kernel(const float* __restrict__ s0, const float* __restrict__ s1,
                     const float* __restrict__ s2, const float* __restrict__ s3,
                     const float* __restrict__ s4, const float* __restrict__ s5,
                     const float* __restrict__ s6, const float* __restrict__ s7,
                     unsigned short* __restrict__ d0, unsigned short* __restrict__ d1,
                     unsigned short* __restrict__ d2, unsigned short* __restrict__ d3,
                     unsigned short* __restrict__ d4, unsigned short* __restrict__ d5,
                     unsigned short* __restrict__ d6, unsigned short* __restrict__ d7) {
    int b = blockIdx.x;
    const float* src; unsigned short* dst;
    if      (b < 1024)  { src = s0; dst = d0; }
    else if (b < 2048)  { src = s1; dst = d1; b -= 1024; }
    else if (b < 3072)  { src = s2; dst = d2; b -= 2048; }
    else if (b < 4096)  { src = s3; dst = d3; b -= 3072; }
    else if (b < 5120)  { src = s4; dst = d4; b -= 4096; }
    else if (b < 8704)  { src = s5; dst = d5; b -= 5120; }
    else if (b < 9728)  { src = s6; dst = d6; b -= 8704; }
    else                { src = s7; dst = d7; b -= 9728; }
    int i = (b * 256 + threadIdx.x) * 4;
    float4 v = *(const float4*)(src + i);
    ushort4 o;
    o.x = f2bf(v.x); o.y = f2bf(v.y); o.z = f2bf(v.z); o.w = f2bf(v.w);
    *(ushort4*)(dst + i) = o;
}

// ---------------- block reduction helper (256 threads) ----------------
__device__ __forceinline__ void blockred2(float& a, float& b, float* sm) {
#pragma unroll
    for (int m = 1; m < 64; m <<= 1) { a += __shfl_xor(a, m); b += __shfl_xor(b, m); }
    const int w = threadIdx.x >> 6;
    __syncthreads();
    if ((threadIdx.x & 63) == 0) { sm[w] = a; sm[4 + w] = b; }
    __syncthreads();
    a = sm[0] + sm[1] + sm[2] + sm[3];
    b = sm[4] + sm[5] + sm[6] + sm[7];
}

// ---------------- ln0 + ln1 fused: x -> x0 (fp32), xn (bf16) ----------------
__global__ __launch_bounds__(256)
void ln01_kernel(const float* __restrict__ x,
                 const float* __restrict__ w0, const float* __restrict__ b0,
                 const float* __restrict__ w1, const float* __restrict__ b1,
                 float* __restrict__ x0, unsigned short* __restrict__ xn) {
    __shared__ float sm[8];
    const int tok = blockIdx.x, tid = threadIdx.x, c = tid * 4;
    const size_t base = (size_t)tok * Cq + c;
    float4 v = *(const float4*)(x + base);
    float s = v.x + v.y + v.z + v.w;
    float ss = v.x * v.x + v.y * v.y + v.z * v.z + v.w * v.w;
    blockred2(s, ss, sm);
    float mu = s * (1.f / Cq);
    float rstd = rsqrtf(ss * (1.f / Cq) - mu * mu + EPSq);
    float4 wv = *(const float4*)(w0 + c), bv = *(const float4*)(b0 + c);
    float4 e;
    e.x = (v.x - mu) * rstd * wv.x + bv.x;
    e.y = (v.y - mu) * rstd * wv.y + bv.y;
    e.z = (v.z - mu) * rstd * wv.z + bv.z;
    e.w = (v.w - mu) * rstd * wv.w + bv.w;
    *(float4*)(x0 + base) = e;
    s = e.x + e.y + e.z + e.w;
    ss = e.x * e.x + e.y * e.y + e.z * e.z + e.w * e.w;
    blockred2(s, ss, sm);
    mu = s * (1.f / Cq);
    rstd = rsqrtf(ss * (1.f / Cq) - mu * mu + EPSq);
    wv = *(const float4*)(w1 + c); bv = *(const float4*)(b1 + c);
    ushort4 o;
    o.x = f2bf((e.x - mu) * rstd * wv.x + bv.x);
    o.y = f2bf((e.y - mu) * rstd * wv.y + bv.y);
    o.z = f2bf((e.z - mu) * rstd * wv.z + bv.z);
    o.w = f2bf((e.w - mu) * rstd * wv.w + bv.w);
    *(ushort4*)(xn + base) = o;
}

// ---------------- single layernorm (ln2): fp32 in -> bf16 out ----------------
__global__ __launch_bounds__(256)
void ln_kernel(const float* __restrict__ x, const float* __restrict__ w,
               const float* __restrict__ b, unsigned short* __restrict__ out) {
    __shared__ float sm[8];
    const int tok = blockIdx.x, tid = threadIdx.x, c = tid * 4;
    const size_t base = (size_t)tok * Cq + c;
    float4 v = *(const float4*)(x + base);
    float s = v.x + v.y + v.z + v.w;
    float ss = v.x * v.x + v.y * v.y + v.z * v.z + v.w * v.w;
    blockred2(s, ss, sm);
    float mu = s * (1.f / Cq);
    float rstd = rsqrtf(ss * (1.f / Cq) - mu * mu + EPSq);
    float4 wv = *(const float4*)(w + c), bv = *(const float4*)(b + c);
    ushort4 o;
    o.x = f2bf((v.x - mu) * rstd * wv.x + bv.x);
    o.y = f2bf((v.y - mu) * rstd * wv.y + bv.y);
    o.z = f2bf((v.z - mu) * rstd * wv.z + bv.z);
    o.w = f2bf((v.w - mu) * rstd * wv.w + bv.w);
    *(ushort4*)(out + base) = o;
}

// ---------------- token-shift: 4 mixes in one pass (time-mix) ----------------
__device__ __forceinline__ ushort4 mixpack(float ax, float ay, float az, float aw,
                                           float px, float py, float pz, float pw,
                                           const float4& m) {
    ushort4 o;
    o.x = f2bf(px + m.x * (ax - px));
    o.y = f2bf(py + m.y * (ay - py));
    o.z = f2bf(pz + m.z * (az - pz));
    o.w = f2bf(pw + m.w * (aw - pw));
    return o;
}

__global__ __launch_bounds__(256)
void mix4_kernel(const unsigned short* __restrict__ xn,
                 const float* __restrict__ tmr, const float* __restrict__ tmk,
                 const float* __restrict__ tmv, const float* __restrict__ tmg,
                 ushort4* __restrict__ outR, ushort4* __restrict__ outK,
                 ushort4* __restrict__ outV, ushort4* __restrict__ outG) {
    const int tok = blockIdx.x, tid = threadIdx.x, c = tid * 4;
    const int t = tok & (Tq - 1);
    const size_t base = (size_t)tok * Cq + c;
    ushort4 a = *(const ushort4*)(xn + base);
    ushort4 p = make_ushort4(0, 0, 0, 0);
    if (t) p = *(const ushort4*)(xn + base - Cq);
    float ax = bf2f(a.x), ay = bf2f(a.y), az = bf2f(a.z), aw = bf2f(a.w);
    float px = bf2f(p.x), py = bf2f(p.y), pz = bf2f(p.z), pw = bf2f(p.w);
    const size_t b4 = (size_t)tok * 256 + tid;
    outR[b4] = mixpack(ax, ay, az, aw, px, py, pz, pw, *(const float4*)(tmr + c));
    outK[b4] = mixpack(ax, ay, az, aw, px, py, pz, pw, *(const float4*)(tmk + c));
    outV[b4] = mixpack(ax, ay, az, aw, px, py, pz, pw, *(const float4*)(tmv + c));
    outG[b4] = mixpack(ax, ay, az, aw, px, py, pz, pw, *(const float4*)(tmg + c));
}

// ---------------- token-shift: 2 mixes in one pass (channel-mix) -------------
__global__ __launch_bounds__(256)
void mix2_kernel(const unsigned short* __restrict__ xn,
                 const float* __restrict__ tmk, const float* __restrict__ tmr,
                 ushort4* __restrict__ outK, ushort4* __restrict__ outR) {
    const int tok = blockIdx.x, tid = threadIdx.x, c = tid * 4;
    const int t = tok & (Tq - 1);
    const size_t base = (size_t)tok * Cq + c;
    ushort4 a = *(const ushort4*)(xn + base);
    ushort4 p = make_ushort4(0, 0, 0, 0);
    if (t) p = *(const ushort4*)(xn + base - Cq);
    float ax = bf2f(a.x), ay = bf2f(a.y), az = bf2f(a.z), aw = bf2f(a.w);
    float px = bf2f(p.x), py = bf2f(p.y), pz = bf2f(p.z), pw = bf2f(p.w);
    const size_t b4 = (size_t)tok * 256 + tid;
    outK[b4] = mixpack(ax, ay, az, aw, px, py, pz, pw, *(const float4*)(tmk + c));
    outR[b4] = mixpack(ax, ay, az, aw, px, py, pz, pw, *(const float4*)(tmr + c));
}

// ---------------- 256x256 phase-pipelined bf16 MFMA GEMM ---------------------
// out[m,n] = sum_k A[m,k]*W[n,k].  8 waves (2Mx4N), per-wave 128x64 output.
// BK=32; LDS = 4-slot ring x {A,B} x 16KB = 128 KiB (1 block/CU, 2 waves/SIMD).
// Pipeline: stage K-tile t+3 while computing t; raw s_barrier (no vmcnt drain);
// counted s_waitcnt vmcnt(8) once per tile; tail drains 8->4->0.
// LDS swizzle (conflict-free): chunk ^= s(row), s(row)=(row^(row>>2))&3.
// Quarter-wave (16 lanes, row stride 64B): even l15 lanes spread 2-per-16B-slot
// over banks 0-15, odd over 16-31 -> 2 lanes/bank = free (m136).  Applied to
// BOTH the pre-swizzled global staging source (linear gload_lds dest) and the
// ds_read_b128 fragment reads (rule #21: same involution both sides).
// MODE: 1 silu->bf16; 2 res+acc->fp32; 3 relu^2->bf16; 4 sigmoid->bf16;
//       5 res+bf2f(sg)*acc->fp32; 6 plain->bf16.  Requires K%32==0, K>=128,
//       M%256==0, N%256==0, grid%8==0 (all call sites satisfy).
template<int MODE>
__global__ __launch_bounds__(512, 2)
void gemm256(const unsigned short* __restrict__ A, const unsigned short* __restrict__ W,
             int K, int N, float* __restrict__ outF, unsigned short* __restrict__ outB,
             const float* __restrict__ res, const unsigned short* __restrict__ sg) {
    __shared__ unsigned short lds[4][2][8192];   // [slot][A=0/B=1][256*32 elems]
    const int tid = threadIdx.x;
    const int wid = tid >> 6, lane = tid & 63;
    const int wr = wid >> 2, wc = wid & 3;       // wave grid 2 (M) x 4 (N)
    const int l15 = lane & 15, q = lane >> 4;

    // T1: bijective XCD swizzle (grid % 8 == 0), then m-major over nn n-blocks
    const int nn = N >> 8;
    const int q8 = gridDim.x >> 3;
    const int bid = blockIdx.x;
    const int swz = (bid & 7) * q8 + (bid >> 3);
    const int m0 = (swz / nn) * 256;
    const int n0 = (swz % nn) * 256;

    // staging: thread's linear LDS dest d -> pre-swizzled global source.
    // dest byte d: row r=d>>6, chunk k=(d>>4)&3; source chunk = k ^ s(r),
    // s(r) = (r ^ (r>>2)) & 3 = (((d>>6) ^ (d>>8)) & 3).
    const int d0 = tid * 16, d1 = 8192 + tid * 16;           // bytes in 16KB region
    const int p0 = d0 ^ ((((d0 >> 6) ^ (d0 >> 8)) & 3) << 4);
    const int p1 = d1 ^ ((((d1 >> 6) ^ (d1 >> 8)) & 3) << 4);
    const int r0 = p0 >> 6, c0 = (p0 >> 1) & 31;             // rows 0..127
    const int r1 = p1 >> 6, c1 = (p1 >> 1) & 31;             // rows 128..255
    const unsigned short* a0 = A + (size_t)(m0 + r0) * K + c0;
    const unsigned short* a1 = A + (size_t)(m0 + r1) * K + c1;
    const unsigned short* w0 = W + (size_t)(n0 + r0) * K + c0;
    const unsigned short* w1 = W + (size_t)(n0 + r1) * K + c1;

    // fragment read offsets (elems): chunk = q ^ s(row); all fragment row
    // bases are multiples of 16, so s(row) = (l15 ^ (l15>>2)) & 3.
    const int cOff = (q ^ ((l15 ^ (l15 >> 2)) & 3)) * 8;
    const int aBase = (wr * 128 + l15) * 32 + cOff;
    const int bBase = (wc * 64 + l15) * 32 + cOff;

    f32x4 acc[8][4];
#pragma unroll
    for (int mi = 0; mi < 8; ++mi)
#pragma unroll
        for (int ni = 0; ni < 4; ++ni)
            acc[mi][ni] = {0.f, 0.f, 0.f, 0.f};

    const int NT = K >> 5;

    // prologue: stage tiles 0,1,2 (12 loads) -> wait 4 oldest (tile 0) landed
#pragma unroll
    for (int t = 0; t < 3; ++t) {
        unsigned short* La = (unsigned short*)&lds[t][0][wid * 512];
        unsigned short* Lb = (unsigned short*)&lds[t][1][wid * 512];
        gload16(a0, La); gload16(a1, La + 4096);
        gload16(w0, Lb); gload16(w1, Lb + 4096);
        a0 += 32; a1 += 32; w0 += 32; w1 += 32;
    }
    asm volatile("s_waitcnt vmcnt(8)" ::: "memory");
    __builtin_amdgcn_s_barrier();

    for (int t = 0; t < NT; ++t) {
        const int slot = t & 3;
        const bool st = (t + 3) < NT;
        const int ps = (t + 3) & 3;
        bf8v af[4], bb[4];

        // ---- phase 1: read af[0:4] + b[0:4] (8 ds_read), stage A(t+3),
        //      16 MFMA (mi 0..3 x ni 0..3) ----
#pragma unroll
        for (int mi = 0; mi < 4; ++mi)
            af[mi] = *(const bf8v*)&lds[slot][0][aBase + mi * 512];
#pragma unroll
        for (int ni = 0; ni < 4; ++ni)
            bb[ni] = *(const bf8v*)&lds[slot][1][bBase + ni * 512];
        if (st) {
            unsigned short* La = (unsigned short*)&lds[ps][0][wid * 512];
            gload16(a0, La); gload16(a1, La + 4096);
            a0 += 32; a1 += 32;
        }
        __builtin_amdgcn_s_barrier();
        __builtin_amdgcn_s_setprio(1);
#pragma unroll
        for (int mi = 0; mi < 4; ++mi)
#pragma unroll
            for (int ni = 0; ni < 4; ++ni)
                acc[mi][ni] = __builtin_amdgcn_mfma_f32_16x16x32_bf16(af[mi], bb[ni], acc[mi][ni], 0, 0, 0);
        __builtin_amdgcn_s_setprio(0);
        __builtin_amdgcn_s_barrier();

        // ---- phase 2: read af[4:8] (4 ds_read), stage B(t+3),
        //      16 MFMA (mi 4..7 x ni 0..3) ----
#pragma unroll
        for (int mi = 0; mi < 4; ++mi)
            af[mi] = *(const bf8v*)&lds[slot][0][aBase + (4 + mi) * 512];
        if (st) {
            unsigned short* Lb = (unsigned short*)&lds[ps][1][wid * 512];
            gload16(w0, Lb); gload16(w1, Lb + 4096);
            w0 += 32; w1 += 32;
        }
        __builtin_amdgcn_s_barrier();
        __builtin_amdgcn_s_setprio(1);
#pragma unroll
        for (int mi = 0; mi < 4; ++mi)
#pragma unroll
            for (int ni = 0; ni < 4; ++ni)
                acc[4 + mi][ni] = __builtin_amdgcn_mfma_f32_16x16x32_bf16(af[mi], bb[ni], acc[4 + mi][ni], 0, 0, 0);
        __builtin_amdgcn_s_setprio(0);
        // counted wait BEFORE the tile-end barrier: after the barrier every
        // wave's loads for tile t+1 have landed.  never 0 in steady state.
        if (t < NT - 3)       { asm volatile("s_waitcnt vmcnt(8)" ::: "memory"); }
        else if (t == NT - 3) { asm volatile("s_waitcnt vmcnt(4)" ::: "memory"); }
        else if (t == NT - 2) { asm volatile("s_waitcnt vmcnt(0)" ::: "memory"); }
        __builtin_amdgcn_s_barrier();
    }

    // ---- epilogue ----
#pragma unroll
    for (int mi = 0; mi < 8; ++mi)
#pragma unroll
        for (int ni = 0; ni < 4; ++ni)
#pragma unroll
            for (int j = 0; j < 4; ++j) {
                const int row = m0 + wr * 128 + mi * 16 + q * 4 + j;
                const int col = n0 + wc * 64 + ni * 16 + l15;
                const size_t idx = (size_t)row * N + col;
                const float a = acc[mi][ni][j];
                if (MODE == 1) {
                    outB[idx] = f2bf(a / (1.f + __expf(-a)));
                } else if (MODE == 2) {
                    outF[idx] = res[idx] + a;
                } else if (MODE == 3) {
                    float tt = fmaxf(a, 0.f);
                    outB[idx] = f2bf(tt * tt);
                } else if (MODE == 4) {
                    outB[idx] = f2bf(1.f / (1.f + __expf(-a)));
                } else if (MODE == 5) {
                    outF[idx] = res[idx] + bf2f(sg[idx]) * a;
                } else {
                    outB[idx] = f2bf(a);
                }
            }
}

// ---------------- WKV5: chunked linear attention + fused GroupNorm*gate ------
__global__ __launch_bounds__(256)
void wkv_kernel(const unsigned short* __restrict__ r, const unsigned short* __restrict__ k,
                const unsigned short* __restrict__ v, const unsigned short* __restrict__ g,
                const float* __restrict__ decay, const float* __restrict__ faaaa,
                const float* __restrict__ lnxw, const float* __restrict__ lnxb,
                unsigned short* __restrict__ ao) {
    __shared__ unsigned short rp[64 * 72], km[64 * 72], kdT[64 * 72];
    __shared__ unsigned short VT[64 * 72], Abf[64 * 72], ScT[64 * 72], Gsh[64 * 72];
    __shared__ float Dt[64];
    const int tid = threadIdx.x;
    const int bh = blockIdx.x, b = bh >> 4, h = bh & 15;
    const int tr = tid >> 2, g4 = tid & 3, i0 = g4 * 16;
    const int wv = tid >> 6, lane = tid & 63, l15 = lane & 15, q = lane >> 4;
    const float LOG2E = 1.44269504088896340736f;

    float l2w[16], uu[16];
#pragma unroll
    for (int ii = 0; ii < 16; ++ii) {
        l2w[ii] = -__expf(decay[h * Nq + i0 + ii]) * LOG2E;
        uu[ii] = faaaa[h * Nq + i0 + ii];
    }
    float ewL[4];
#pragma unroll
    for (int jr = 0; jr < 4; ++jr) {
        float lw = -__expf(decay[h * Nq + 16 * wv + q * 4 + jr]) * LOG2E;
        ewL[jr] = exp2f(64.f * lw);
    }
    const int colbase = h * Nq;
    float lwj[4], lbj[4];
#pragma unroll
    for (int nt = 0; nt < 4; ++nt) {
        lwj[nt] = lnxw[colbase + 16 * nt + l15];
        lbj[nt] = lnxb[colbase + 16 * nt + l15];
    }
    f32x4 S[4];
#pragma unroll
    for (int nt = 0; nt < 4; ++nt) S[nt] = {0.f, 0.f, 0.f, 0.f};
    for (int idx = tid; idx < 64 * 72; idx += 256) ScT[idx] = 0;
    __syncthreads();

    const size_t rowbase = (size_t)b * Tq;

    for (int c = 0; c < 32; ++c) {
        const size_t grow = (rowbase + c * 64 + tr) * Cq + colbase + i0;
        unsigned short rs_[16], ks_[16], vs_[16];
        *(uint4*)&rs_[0] = *(const uint4*)(r + grow);
        *(uint4*)&rs_[8] = *(const uint4*)(r + grow + 8);
        *(uint4*)&ks_[0] = *(const uint4*)(k + grow);
        *(uint4*)&ks_[8] = *(const uint4*)(k + grow + 8);
        *(uint4*)&vs_[0] = *(const uint4*)(v + grow);
        *(uint4*)&vs_[8] = *(const uint4*)(v + grow + 8);
        *(uint4*)&Gsh[tr * 72 + i0] = *(const uint4*)(g + grow);
        *(uint4*)&Gsh[tr * 72 + i0 + 8] = *(const uint4*)(g + grow + 8);
        float pd = 0.f;
        const float ftr = (float)tr;
#pragma unroll
        for (int ii = 0; ii < 16; ++ii) {
            float rf = bf2f(rs_[ii]), kf = bf2f(ks_[ii]);
            rp[tr * 72 + i0 + ii] = f2bf(rf * exp2f(ftr * l2w[ii]));
            km[tr * 72 + i0 + ii] = f2bf(kf * exp2f(-(ftr + 1.f) * l2w[ii]));
            kdT[(i0 + ii) * 72 + tr] = f2bf(kf * exp2f((63.f - ftr) * l2w[ii]));
            VT[(i0 + ii) * 72 + tr] = vs_[ii];
            pd += rf * uu[ii] * kf;
        }
        pd += __shfl_xor(pd, 1);
        pd += __shfl_xor(pd, 2);
        if (g4 == 0) Dt[tr] = pd;
        __syncthreads();

        f32x4 accA[4];
#pragma unroll
        for (int nt = 0; nt < 4; ++nt) accA[nt] = {0.f, 0.f, 0.f, 0.f};
#pragma unroll
        for (int ks = 0; ks < 2; ++ks) {
            bf8v a = *(const bf8v*)&rp[(16 * wv + l15) * 72 + ks * 32 + q * 8];
#pragma unroll
            for (int nt = 0; nt < 4; ++nt) {
                bf8v bbv = *(const bf8v*)&km[(16 * nt + l15) * 72 + ks * 32 + q * 8];
                accA[nt] = __builtin_amdgcn_mfma_f32_16x16x32_bf16(a, bbv, accA[nt], 0, 0, 0);
            }
        }
#pragma unroll
        for (int nt = 0; nt < 4; ++nt)
#pragma unroll
            for (int jr = 0; jr < 4; ++jr) {
                const int t = 16 * wv + q * 4 + jr, s = 16 * nt + l15;
                const float a = accA[nt][jr];
                const float val = (s < t) ? a : ((s == t) ? Dt[t] : 0.f);
                Abf[t * 72 + s] = f2bf(val);
            }

        f32x4 accY[4];
#pragma unroll
        for (int nt = 0; nt < 4; ++nt) accY[nt] = {0.f, 0.f, 0.f, 0.f};
#pragma unroll
        for (int ks = 0; ks < 2; ++ks) {
            bf8v a = *(const bf8v*)&Abf[(16 * wv + l15) * 72 + ks * 32 + q * 8];
#pragma unroll
            for (int nt = 0; nt < 4; ++nt) {
                bf8v bbv = *(const bf8v*)&VT[(16 * nt + l15) * 72 + ks * 32 + q * 8];
                accY[nt] = __builtin_amdgcn_mfma_f32_16x16x32_bf16(a, bbv, accY[nt], 0, 0, 0);
            }
        }
#pragma unroll
        for (int ks = 0; ks < 2; ++ks) {
            bf8v a = *(const bf8v*)&rp[(16 * wv + l15) * 72 + ks * 32 + q * 8];
#pragma unroll
            for (int nt = 0; nt < 4; ++nt) {
                bf8v bbv = *(const bf8v*)&ScT[(16 * nt + l15) * 72 + ks * 32 + q * 8];
                accY[nt] = __builtin_amdgcn_mfma_f32_16x16x32_bf16(a, bbv, accY[nt], 0, 0, 0);
            }
        }

        float sum_[4] = {0.f, 0.f, 0.f, 0.f}, sq_[4] = {0.f, 0.f, 0.f, 0.f};
#pragma unroll
        for (int nt = 0; nt < 4; ++nt)
#pragma unroll
            for (int jr = 0; jr < 4; ++jr) {
                float yv = accY[nt][jr] * 0.125f;
                accY[nt][jr] = yv;
                sum_[jr] += yv;
                sq_[jr] += yv * yv;
            }
#pragma unroll
        for (int m = 1; m < 16; m <<= 1)
#pragma unroll
            for (int jr = 0; jr < 4; ++jr) {
                sum_[jr] += __shfl_xor(sum_[jr], m);
                sq_[jr] += __shfl_xor(sq_[jr], m);
            }
        float mu_[4], rstd_[4];
#pragma unroll
        for (int jr = 0; jr < 4; ++jr) {
            mu_[jr] = sum_[jr] * (1.f / Nq);
            rstd_[jr] = rsqrtf(sq_[jr] * (1.f / Nq) - mu_[jr] * mu_[jr] + EPSq);
        }
#pragma unroll
        for (int nt = 0; nt < 4; ++nt)
#pragma unroll
            for (int jr = 0; jr < 4; ++jr) {
                const int t = 16 * wv + q * 4 + jr;
                const float gate = bf2f(Gsh[t * 72 + 16 * nt + l15]);
                const float val = (accY[nt][jr] - mu_[jr]) * rstd_[jr] * lwj[nt] + lbj[nt];
                ao[(rowbase + c * 64 + t) * Cq + colbase + 16 * nt + l15] = f2bf(val * gate);
            }

        f32x4 accU[4];
#pragma unroll
        for (int nt = 0; nt < 4; ++nt) accU[nt] = {0.f, 0.f, 0.f, 0.f};
#pragma unroll
        for (int ks = 0; ks < 2; ++ks) {
            bf8v a = *(const bf8v*)&kdT[(16 * wv + l15) * 72 + ks * 32 + q * 8];
#pragma unroll
            for (int nt = 0; nt < 4; ++nt) {
                bf8v bbv = *(const bf8v*)&VT[(16 * nt + l15) * 72 + ks * 32 + q * 8];
                accU[nt] = __builtin_amdgcn_mfma_f32_16x16x32_bf16(a, bbv, accU[nt], 0, 0, 0);
            }
        }
        __syncthreads();
#pragma unroll
        for (int nt = 0; nt < 4; ++nt) {
#pragma unroll
            for (int jr = 0; jr < 4; ++jr)
                S[nt][jr] = ewL[jr] * S[nt][jr] + accU[nt][jr];
            ushort4 sc;
            sc.x = f2bf(S[nt][0]); sc.y = f2bf(S[nt][1]);
            sc.z = f2bf(S[nt][2]); sc.w = f2bf(S[nt][3]);
            *(ushort4*)&ScT[(16 * nt + l15) * 72 + 16 * wv + q * 4] = sc;
        }
        __syncthreads();
    }
}

// ---------------- launcher ----------------
extern "C" void kernel_launch(void* const* d_in, const int* in_sizes, int n_in,
                              void* d_out, int out_size, void* d_ws, size_t ws_size,
                              hipStream_t stream) {
    const float* x     = (const float*)d_in[0];
    const float* ln0w  = (const float*)d_in[1];
    const float* ln0b  = (const float*)d_in[2];
    const float* ln1w  = (const float*)d_in[3];
    const float* ln1b  = (const float*)d_in[4];
    const float* ln2w  = (const float*)d_in[5];
    const float* ln2b  = (const float*)d_in[6];
    const float* atmk  = (const float*)d_in[7];
    const float* atmv  = (const float*)d_in[8];
    const float* atmr  = (const float*)d_in[9];
    const float* atmg  = (const float*)d_in[10];
    const float* decay = (const float*)d_in[11];
    const float* faaaa = (const float*)d_in[12];
    const float* aWr   = (const float*)d_in[13];
    const float* aWk   = (const float*)d_in[14];
    const float* aWv   = (const float*)d_in[15];
    const float* aWg   = (const float*)d_in[16];
    const float* aWo   = (const float*)d_in[17];
    const float* lnxw  = (const float*)d_in[18];
    const float* lnxb  = (const float*)d_in[19];
    const float* ftmk  = (const float*)d_in[20];
    const float* ftmr  = (const float*)d_in[21];
    const float* fWk   = (const float*)d_in[22];
    const float* fWr   = (const float*)d_in[23];
    const float* fWv   = (const float*)d_in[24];

    const size_t MB = 1024ull * 1024ull;
    const size_t WS_NEEDED = 250 * MB;
    dim3 blk(256);

    if (ws_size < WS_NEEDED) {
        diag_kernel<<<out_size / 1024, blk, 0, stream>>>((float*)d_out,
            1000.f + (float)((double)ws_size / (double)MB));
        return;
    }

    char* ws = (char*)d_ws;
    unsigned short* WR  = (unsigned short*)(ws + 0 * MB);
    unsigned short* WK  = (unsigned short*)(ws + 2 * MB);
    unsigned short* WV  = (unsigned short*)(ws + 4 * MB);
    unsigned short* WG  = (unsigned short*)(ws + 6 * MB);
    unsigned short* WO  = (unsigned short*)(ws + 8 * MB);
    unsigned short* FWK = (unsigned short*)(ws + 10 * MB);
    unsigned short* FWR = (unsigned short*)(ws + 17 * MB);
    unsigned short* FWV = (unsigned short*)(ws + 19 * MB);
    unsigned short* XN  = (unsigned short*)(ws + 26 * MB);
    unsigned short* MXR = (unsigned short*)(ws + 58 * MB);
    unsigned short* MXK = (unsigned short*)(ws + 90 * MB);
    unsigned short* MXV = (unsigned short*)(ws + 122 * MB);
    unsigned short* MXG = (unsigned short*)(ws + 154 * MB);
    unsigned short* Rb  = (unsigned short*)(ws + 186 * MB);
    unsigned short* Kb  = (unsigned short*)(ws + 58 * MB);
    unsigned short* Vb  = (unsigned short*)(ws + 90 * MB);
    unsigned short* Gb  = (unsigned short*)(ws + 122 * MB);
    unsigned short* AO  = (unsigned short*)(ws + 154 * MB);
    unsigned short* XK2 = (unsigned short*)(ws + 58 * MB);
    unsigned short* XR2 = (unsigned short*)(ws + 90 * MB);
    unsigned short* KF  = (unsigned short*)(ws + 122 * MB);
    unsigned short* SRb = (unsigned short*)(ws + 26 * MB);
    float*          X0  = (float*)d_out;

    const int NTOK = Bq * Tq;  // 16384
    dim3 blk512(512);
    const int gsq = (NTOK / 256) * (Cq / 256);    // 64*4  = 256 blocks
    const int gup = (NTOK / 256) * (FFNq / 256);  // 64*14 = 896 blocks

    f2bf_all_kernel<<<13312, blk, 0, stream>>>(aWr, aWk, aWv, aWg, aWo, fWk, fWr, fWv,
                                               WR, WK, WV, WG, WO, FWK, FWR, FWV);

    ln01_kernel<<<NTOK, blk, 0, stream>>>(x, ln0w, ln0b, ln1w, ln1b, X0, XN);

    mix4_kernel<<<NTOK, blk, 0, stream>>>(XN, atmr, atmk, atmv, atmg,
                                          (ushort4*)MXR, (ushort4*)MXK,
                                          (ushort4*)MXV, (ushort4*)MXG);

    gemm256<6><<<gsq, blk512, 0, stream>>>(MXR, WR, Cq, Cq, nullptr, Rb, nullptr, nullptr);
    gemm256<6><<<gsq, blk512, 0, stream>>>(MXK, WK, Cq, Cq, nullptr, Kb, nullptr, nullptr);
    gemm256<6><<<gsq, blk512, 0, stream>>>(MXV, WV, Cq, Cq, nullptr, Vb, nullptr, nullptr);
    gemm256<1><<<gsq, blk512, 0, stream>>>(MXG, WG, Cq, Cq, nullptr, Gb, nullptr, nullptr);

    wkv_kernel<<<Bq * Hq, blk, 0, stream>>>(Rb, Kb, Vb, Gb, decay, faaaa, lnxw, lnxb, AO);
    gemm256<2><<<gsq, blk512, 0, stream>>>(AO, WO, Cq, Cq, X0, nullptr, X0, nullptr);

    ln_kernel<<<NTOK, blk, 0, stream>>>(X0, ln2w, ln2b, XN);
    mix2_kernel<<<NTOK, blk, 0, stream>>>(XN, ftmk, ftmr, (ushort4*)XK2, (ushort4*)XR2);
    gemm256<3><<<gup, blk512, 0, stream>>>(XK2, FWK, Cq, FFNq, nullptr, KF, nullptr, nullptr);
    gemm256<4><<<gsq, blk512, 0, stream>>>(XR2, FWR, Cq, Cq, nullptr, SRb, nullptr, nullptr);
    gemm256<5><<<gsq, blk512, 0, stream>>>(KF, FWV, FFNq, Cq, X0, nullptr, X0, SRb);
}